// Round 13
// baseline (270.913 us; speedup 1.0000x reference)
//
#include <hip/hip_runtime.h>
#include <hip/hip_bf16.h>

typedef __attribute__((ext_vector_type(8))) short bf16x8;
typedef __attribute__((ext_vector_type(4))) short bf16x4;
typedef __attribute__((ext_vector_type(4))) float f32x4;

#define LDS_PAD 72
#define LOG2E 1.44269504088896f

static __device__ __forceinline__ float bf2f(__hip_bfloat16 v) { return __bfloat162float(v); }

// load 8 consecutive f32, round to bf16x8
static __device__ __forceinline__ bf16x8 ld8f_bf16(const float* __restrict__ p) {
    const float4 a = *(const float4*)p;
    const float4 b = *(const float4*)(p + 4);
    bf16x8 r;
    __hip_bfloat16* h = (__hip_bfloat16*)&r;
    h[0] = __float2bfloat16(a.x); h[1] = __float2bfloat16(a.y);
    h[2] = __float2bfloat16(a.z); h[3] = __float2bfloat16(a.w);
    h[4] = __float2bfloat16(b.x); h[5] = __float2bfloat16(b.y);
    h[6] = __float2bfloat16(b.z); h[7] = __float2bfloat16(b.w);
    return r;
}

// async global->LDS, 16B per lane; lds base must be wave-uniform
static __device__ __forceinline__ void gload_lds16(const __hip_bfloat16* g, __hip_bfloat16* l) {
    __builtin_amdgcn_global_load_lds(
        (const __attribute__((address_space(1))) void*)g,
        (__attribute__((address_space(3))) void*)l, 16, 0, 0);
}

// ---------------------------------------------------------------------------
// Kernel 0: f32 -> bf16 conversion for wo only (qkv converts inline now).
// ---------------------------------------------------------------------------
__global__ __launch_bounds__(256) void cvt_wo(const float* __restrict__ src,
                                              __hip_bfloat16* __restrict__ dst) {
    const int i = (blockIdx.x * 256 + threadIdx.x) * 8;
    *(bf16x8*)(dst + i) = ld8f_bf16(src + i);
}

// ---------------------------------------------------------------------------
// Kernel 1: fused QKV projection, 512 threads / 8 waves (wave tile 32x64).
// Register-prefetch staging reading f32 x/weights DIRECTLY, converting to
// bf16 in-reg before ds_write (cvt_x / cvt_w eliminated). Next K-tile's
// loads issued after barrier-2 -> latency hidden under compute.
// q pre-scaled by log2(e) for exp2 softmax.
// Outputs:
//   qr, kr : [((b*12+nh)*1024 + l)*64 + d]
//   v_t    : [((b*12+nh)*64 + d)*1024 + l]
// ---------------------------------------------------------------------------
__global__ __launch_bounds__(512) void qkv_gemm(
    const float* __restrict__ x,
    const float* __restrict__ wq, const float* __restrict__ wk,
    const float* __restrict__ wv,
    const float* __restrict__ bq, const float* __restrict__ bk,
    const float* __restrict__ bv,
    const float* __restrict__ sinp, const float* __restrict__ cosp,
    __hip_bfloat16* __restrict__ qr, __hip_bfloat16* __restrict__ kr,
    __hip_bfloat16* __restrict__ v_t)
{
    __shared__ __align__(16) __hip_bfloat16 Alds[128 * 64];
    __shared__ __align__(16) __hip_bfloat16 Blds[128 * 64];

    const int t    = threadIdx.x;
    const int lane = t & 63;
    const int w    = t >> 6;           // 0..7
    const int wm   = w >> 1, wn = w & 1;
    const int l15  = lane & 15, lhi = lane >> 4;

    const int rm   = blockIdx.x;       // row tile 0..63
    const int cy   = blockIdx.y;       // 0..17
    const int wsel = cy / 6;           // 0=q,1=k,2=v
    const int cn   = cy % 6;

    const float* wgt  = (wsel == 0) ? wq : (wsel == 1) ? wk : wv;
    const float* bias = (wsel == 0) ? bq : (wsel == 1) ? bk : bv;

    // staging geometry: thread covers rows {w*16+(lane>>3)+8j}, cols (lane&7)*8
    const int srow = w * 16 + (lane >> 3);
    const int scol = (lane & 7) * 8;
    const int lds_off = srow * 64 + scol;
    const float* asrc = x   + (size_t)(rm * 128 + srow) * 768 + scol;
    const float* bsrc = wgt + (size_t)(cn * 128 + srow) * 768 + scol;

    f32x4 acc[2][4] = {};

    // prologue: prefetch + convert K-tile 0
    bf16x8 ar[2], br[2];
    #pragma unroll
    for (int j = 0; j < 2; ++j) {
        ar[j] = ld8f_bf16(asrc + (size_t)j * 8 * 768);
        br[j] = ld8f_bf16(bsrc + (size_t)j * 8 * 768);
    }

    for (int k0 = 0; k0 < 768; k0 += 64) {
        __syncthreads();   // previous compute done, LDS reusable
        #pragma unroll
        for (int j = 0; j < 2; ++j) {
            *(bf16x8*)&Alds[lds_off + j * 8 * 64] = ar[j];
            *(bf16x8*)&Blds[lds_off + j * 8 * 64] = br[j];
        }
        __syncthreads();   // writes visible
        if (k0 + 64 < 768) {   // prefetch next tile; hidden under compute
            #pragma unroll
            for (int j = 0; j < 2; ++j) {
                ar[j] = ld8f_bf16(asrc + (size_t)j * 8 * 768 + k0 + 64);
                br[j] = ld8f_bf16(bsrc + (size_t)j * 8 * 768 + k0 + 64);
            }
        }
        #pragma unroll
        for (int kk = 0; kk < 2; ++kk) {
            bf16x8 af[2], bfr[4];
            #pragma unroll
            for (int m = 0; m < 2; ++m)
                af[m] = *(const bf16x8*)&Alds[(wm * 32 + m * 16 + l15) * 64 + kk * 32 + lhi * 8];
            #pragma unroll
            for (int n = 0; n < 4; ++n)
                bfr[n] = *(const bf16x8*)&Blds[(wn * 64 + n * 16 + l15) * 64 + kk * 32 + lhi * 8];
            #pragma unroll
            for (int m = 0; m < 2; ++m)
                #pragma unroll
                for (int n = 0; n < 4; ++n)
                    acc[m][n] = __builtin_amdgcn_mfma_f32_16x16x32_bf16(af[m], bfr[n], acc[m][n], 0, 0, 0);
        }
    }

    // Epilogue: bias, RoPE (q,k), scaling (k: 0.125, q: log2e), scatter.
    #pragma unroll
    for (int m = 0; m < 2; ++m) {
        #pragma unroll
        for (int n = 0; n < 4; ++n) {
            const int gcol = cn * 128 + wn * 64 + n * 16 + l15;   // 0..767
            const float bcol = bias[gcol];
            const int nh = gcol >> 6, d = gcol & 63;
            const int grow0 = rm * 128 + wm * 32 + m * 16 + lhi * 4;
            const int bb = grow0 >> 10, ll0 = grow0 & 1023;
            if (wsel == 2) {
                bf16x4 pk;
                #pragma unroll
                for (int r = 0; r < 4; ++r)
                    ((__hip_bfloat16*)&pk)[r] = __float2bfloat16(acc[m][n][r] + bcol);
                *(bf16x4*)&v_t[(size_t)((bb * 12 + nh) * 64 + d) * 1024 + ll0] = pk;
            } else {
                #pragma unroll
                for (int r = 0; r < 4; ++r) {
                    const int ll = ll0 + r;
                    const float val = acc[m][n][r] + bcol;
                    const float other = __shfl_xor(val, 1);
                    const float cs = cosp[ll * 64 + d];
                    const float sn = sinp[ll * 64 + d];
                    float res = val * cs + ((d & 1) ? other : -other) * sn;
                    res *= (wsel == 1) ? 0.125f : LOG2E;
                    __hip_bfloat16* dst = (wsel == 1) ? kr : qr;
                    dst[(size_t)((bb * 12 + nh) * 1024 + ll) * 64 + d] = __float2bfloat16(res);
                }
            }
        }
    }
}

// ---------------------------------------------------------------------------
// Kernel 2: flash-style attention, swapped-operand, LDS-staged K/V with
// register prefetch; static exp2 softmax. NEW: mask register-prefetched one
// kt ahead (with K/V) — mask is only L3-resident, so the un-prefetched load
// was a ~500-900 cyc stall feeding softmax every iteration.
// ---------------------------------------------------------------------------
__global__ __launch_bounds__(256) void attn_kernel(
    const __hip_bfloat16* __restrict__ qr,
    const __hip_bfloat16* __restrict__ kr,
    const __hip_bfloat16* __restrict__ v_t,
    const float* __restrict__ mask,
    __hip_bfloat16* __restrict__ attn_out)
{
    __shared__ __align__(16) __hip_bfloat16 Klds[64][LDS_PAD];
    __shared__ __align__(16) __hip_bfloat16 Vtlds[64][LDS_PAD];
    __shared__ __align__(16) __hip_bfloat16 Pq[4][16][LDS_PAD];

    const int qt = blockIdx.x;      // 0..15
    const int bh = blockIdx.y;      // 0..95
    const int b = bh / 12, nh = bh % 12;

    const int t = threadIdx.x, lane = t & 63, w = t >> 6;
    const int l15 = lane & 15, lhi = lane >> 4;
    const int qg = qt * 64 + w * 16 + l15;

    bf16x8 qf[2];   // q pre-scaled by log2(e)
    qf[0] = *(const bf16x8*)&qr[((size_t)bh * 1024 + qg) * 64 + lhi * 8];
    qf[1] = *(const bf16x8*)&qr[((size_t)bh * 1024 + qg) * 64 + 32 + lhi * 8];

    f32x4 o[4] = {};
    float l_run = 0.f;

    const int srow = t >> 3;
    const int scol = (t & 7) * 8;

    const float* mbase = mask + ((size_t)nh << 20) + (size_t)qg * 1024;

    // prologue: prefetch kt=0 K/V tiles and mask
    bf16x8 kb0, kb1, vb0, vb1;
    float4 mv[4];
    {
        const size_t kbase = ((size_t)bh * 1024) * 64;
        kb0 = *(const bf16x8*)&kr[kbase + (size_t)srow * 64 + scol];
        kb1 = *(const bf16x8*)&kr[kbase + (size_t)(srow + 32) * 64 + scol];
        const size_t vbase = (size_t)bh * 64 * 1024;
        vb0 = *(const bf16x8*)&v_t[vbase + (size_t)srow * 1024 + scol];
        vb1 = *(const bf16x8*)&v_t[vbase + (size_t)(srow + 32) * 1024 + scol];
        #pragma unroll
        for (int n = 0; n < 4; ++n)
            mv[n] = *(const float4*)&mbase[n * 16 + lhi * 4];
    }

    for (int kt = 0; kt < 16; ++kt) {
        *(bf16x8*)&Klds[srow][scol]       = kb0;
        *(bf16x8*)&Klds[srow + 32][scol]  = kb1;
        *(bf16x8*)&Vtlds[srow][scol]      = vb0;
        *(bf16x8*)&Vtlds[srow + 32][scol] = vb1;
        __syncthreads();

        float4 mvn[4];
        if (kt < 15) {   // prefetch next tile's K/V AND mask
            const size_t kbase = ((size_t)bh * 1024 + (kt + 1) * 64) * 64;
            kb0 = *(const bf16x8*)&kr[kbase + (size_t)srow * 64 + scol];
            kb1 = *(const bf16x8*)&kr[kbase + (size_t)(srow + 32) * 64 + scol];
            const size_t vbase = (size_t)bh * 64 * 1024 + (kt + 1) * 64;
            vb0 = *(const bf16x8*)&v_t[vbase + (size_t)srow * 1024 + scol];
            vb1 = *(const bf16x8*)&v_t[vbase + (size_t)(srow + 32) * 1024 + scol];
            #pragma unroll
            for (int n = 0; n < 4; ++n)
                mvn[n] = *(const float4*)&mbase[(kt + 1) * 64 + n * 16 + lhi * 4];
        }

        f32x4 s[4] = {};
        __builtin_amdgcn_s_setprio(1);
        #pragma unroll
        for (int n = 0; n < 4; ++n) {
            const bf16x8 kf0 = *(const bf16x8*)&Klds[n * 16 + l15][lhi * 8];
            const bf16x8 kf1 = *(const bf16x8*)&Klds[n * 16 + l15][32 + lhi * 8];
            s[n] = __builtin_amdgcn_mfma_f32_16x16x32_bf16(kf0, qf[0], s[n], 0, 0, 0);
            s[n] = __builtin_amdgcn_mfma_f32_16x16x32_bf16(kf1, qf[1], s[n], 0, 0, 0);
        }
        __builtin_amdgcn_s_setprio(0);

        // static softmax: P = exp2(s + mask*log2e); pure-sum l accumulation
        #pragma unroll
        for (int n = 0; n < 4; ++n) {
            bf16x4 pk;
            #pragma unroll
            for (int r = 0; r < 4; ++r) {
                const float p = exp2f(fmaf(((const float*)&mv[n])[r], LOG2E, s[n][r]));
                l_run += p;
                ((__hip_bfloat16*)&pk)[r] = __float2bfloat16(p);
            }
            *(bf16x4*)&Pq[w][l15][n * 16 + lhi * 4] = pk;
        }
        asm volatile("s_waitcnt lgkmcnt(0)" ::: "memory");
        __builtin_amdgcn_sched_barrier(0);

        __builtin_amdgcn_s_setprio(1);
        #pragma unroll
        for (int ks = 0; ks < 2; ++ks) {
            const bf16x8 pf = *(const bf16x8*)&Pq[w][l15][ks * 32 + lhi * 8];
            #pragma unroll
            for (int m = 0; m < 4; ++m) {
                const bf16x8 vf = *(const bf16x8*)&Vtlds[m * 16 + l15][ks * 32 + lhi * 8];
                o[m] = __builtin_amdgcn_mfma_f32_16x16x32_bf16(vf, pf, o[m], 0, 0, 0);
            }
        }
        __builtin_amdgcn_s_setprio(0);
        __syncthreads();

        #pragma unroll
        for (int n = 0; n < 4; ++n) mv[n] = mvn[n];
    }

    // one final cross-lane l reduce (q row spans lhi = 0..3)
    l_run += __shfl_xor(l_run, 16);
    l_run += __shfl_xor(l_run, 32);

    const float rl = 1.f / l_run;
    #pragma unroll
    for (int m = 0; m < 4; ++m) {
        bf16x4 pk;
        #pragma unroll
        for (int r = 0; r < 4; ++r)
            ((__hip_bfloat16*)&pk)[r] = __float2bfloat16(o[m][r] * rl);
        *(bf16x4*)&attn_out[((size_t)b * 1024 + qg) * 768 + nh * 64 + m * 16 + lhi * 4] = pk;
    }
}

// ---------------------------------------------------------------------------
// Kernel 3: depthwise 5x5 conv (LEPE), fused add into aout (in-place).
// ---------------------------------------------------------------------------
__global__ __launch_bounds__(256) void lepe_conv(
    const __hip_bfloat16* __restrict__ v_t,
    const float* __restrict__ lw,
    const float* __restrict__ lb,
    __hip_bfloat16* __restrict__ aout)
{
    __shared__ __hip_bfloat16 img[8][1024];

    const int b  = blockIdx.x / 96;
    const int cg = blockIdx.x % 96;
    const int c0 = cg * 8;
    const int t  = threadIdx.x;

    for (int i = t; i < 2048; i += 256) {
        const int ci = i >> 8, l4 = (i & 255) << 2;
        const int c = c0 + ci, nh = c >> 6, d = c & 63;
        *(bf16x4*)&img[ci][l4] =
            *(const bf16x4*)&v_t[(size_t)((b * 12 + nh) * 64 + d) * 1024 + l4];
    }
    __syncthreads();

    const int ci = t & 7, c = c0 + ci;
    float wt[25];
    #pragma unroll
    for (int k = 0; k < 25; ++k) wt[k] = lw[k * 768 + c];
    const float bias = lb[c];

    for (int l0 = t >> 3; l0 < 1024; l0 += 32) {
        const int h = l0 >> 5, w = l0 & 31;
        float s = bias;
        #pragma unroll
        for (int dy = 0; dy < 5; ++dy) {
            const int hy = h + dy - 2;
            if (hy < 0 || hy > 31) continue;
            #pragma unroll
            for (int dx = 0; dx < 5; ++dx) {
                const int wx = w + dx - 2;
                if (wx < 0 || wx > 31) continue;
                s += bf2f(img[ci][hy * 32 + wx]) * wt[dy * 5 + dx];
            }
        }
        const size_t idx = (size_t)(b * 1024 + l0) * 768 + c;
        aout[idx] = __float2bfloat16(s + bf2f(aout[idx]));
    }
}

// ---------------------------------------------------------------------------
// Kernel 4: output projection (512 threads / 8 waves, wave tile 32x64,
// gload_lds staging — the r9/r6 known-good version).
// out = aout @ wo^T + bo  (bf16 in, f32 out)
// ---------------------------------------------------------------------------
__global__ __launch_bounds__(512) void proj_gemm(
    const __hip_bfloat16* __restrict__ aout,
    const __hip_bfloat16* __restrict__ wb,
    const float* __restrict__ bo,
    float* __restrict__ out)
{
    __shared__ __align__(16) __hip_bfloat16 Alds[128 * 64];
    __shared__ __align__(16) __hip_bfloat16 Blds[128 * 64];

    const int t    = threadIdx.x;
    const int lane = t & 63;
    const int w    = t >> 6;
    const int wm   = w >> 1, wn = w & 1;
    const int l15  = lane & 15, lhi = lane >> 4;

    const int rm = blockIdx.x, cn = blockIdx.y;

    const int srow = w * 16 + (lane >> 3);
    const int scol = (lane & 7) * 8;
    const __hip_bfloat16* asrc = aout + (size_t)(rm * 128 + srow) * 768 + scol;
    const __hip_bfloat16* bsrc = wb   + (size_t)(cn * 128 + srow) * 768 + scol;

    f32x4 acc[2][4] = {};

    for (int k0 = 0; k0 < 768; k0 += 64) {
        __syncthreads();
        #pragma unroll
        for (int j = 0; j < 2; ++j) {
            gload_lds16(asrc + (size_t)j * 8 * 768 + k0, Alds + (w * 2 + j) * 512);
            gload_lds16(bsrc + (size_t)j * 8 * 768 + k0, Blds + (w * 2 + j) * 512);
        }
        __syncthreads();
        #pragma unroll
        for (int kk = 0; kk < 2; ++kk) {
            bf16x8 af[2], bfr[4];
            #pragma unroll
            for (int m = 0; m < 2; ++m)
                af[m] = *(const bf16x8*)&Alds[(wm * 32 + m * 16 + l15) * 64 + kk * 32 + lhi * 8];
            #pragma unroll
            for (int n = 0; n < 4; ++n)
                bfr[n] = *(const bf16x8*)&Blds[(wn * 64 + n * 16 + l15) * 64 + kk * 32 + lhi * 8];
            #pragma unroll
            for (int m = 0; m < 2; ++m)
                #pragma unroll
                for (int n = 0; n < 4; ++n)
                    acc[m][n] = __builtin_amdgcn_mfma_f32_16x16x32_bf16(af[m], bfr[n], acc[m][n], 0, 0, 0);
        }
    }

    #pragma unroll
    for (int m = 0; m < 2; ++m)
        #pragma unroll
        for (int n = 0; n < 4; ++n) {
            const int gcol = cn * 128 + wn * 64 + n * 16 + l15;
            const float bcol = bo[gcol];
            #pragma unroll
            for (int r = 0; r < 4; ++r) {
                const int grow = rm * 128 + wm * 32 + m * 16 + lhi * 4 + r;
                out[(size_t)grow * 768 + gcol] = acc[m][n][r] + bcol;
            }
        }
}

// ---------------------------------------------------------------------------
extern "C" void kernel_launch(void* const* d_in, const int* in_sizes, int n_in,
                              void* d_out, int out_size, void* d_ws, size_t ws_size,
                              hipStream_t stream) {
    const float* x    = (const float*)d_in[0];
    const float* sinp = (const float*)d_in[1];
    const float* cosp = (const float*)d_in[2];
    const float* mask = (const float*)d_in[3];
    const float* wq   = (const float*)d_in[4];
    const float* bq   = (const float*)d_in[5];
    const float* wk   = (const float*)d_in[6];
    const float* bk   = (const float*)d_in[7];
    const float* wvw  = (const float*)d_in[8];
    const float* bv   = (const float*)d_in[9];
    const float* lw   = (const float*)d_in[10];
    const float* lb   = (const float*)d_in[11];
    const float* wo   = (const float*)d_in[12];
    const float* bo   = (const float*)d_in[13];
    float* out = (float*)d_out;

    char* ws = (char*)d_ws;
    const size_t SZ = (size_t)8192 * 768 * 2;    // 12.58 MB per bf16 buffer
    __hip_bfloat16* qr   = (__hip_bfloat16*)(ws);
    __hip_bfloat16* kr   = (__hip_bfloat16*)(ws + SZ);
    __hip_bfloat16* v_t  = (__hip_bfloat16*)(ws + 2 * SZ);
    __hip_bfloat16* aout = (__hip_bfloat16*)(ws + 3 * SZ);
    __hip_bfloat16* wb   = (__hip_bfloat16*)(ws + 4 * SZ);   // wo bf16 (1.18 MB)

    cvt_wo<<<dim3(288), 256, 0, stream>>>(wo, wb);
    qkv_gemm<<<dim3(64, 18), 512, 0, stream>>>(x, wq, wk, wvw, bq, bk, bv,
                                               sinp, cosp, qr, kr, v_t);
    attn_kernel<<<dim3(16, 96), 256, 0, stream>>>(qr, kr, v_t, mask, aout);
    lepe_conv<<<dim3(768), 256, 0, stream>>>(v_t, lw, lb, aout);
    proj_gemm<<<dim3(64, 6), 512, 0, stream>>>(aout, wb, bo, out);
}

// Round 14
// 238.255 us; speedup vs baseline: 1.1371x; 1.1371x over previous
//
#include <hip/hip_runtime.h>
#include <hip/hip_bf16.h>

typedef __attribute__((ext_vector_type(8))) short bf16x8;
typedef __attribute__((ext_vector_type(4))) short bf16x4;
typedef __attribute__((ext_vector_type(4))) float f32x4;

#define LDS_PAD 72
#define LOG2E 1.44269504088896f

static __device__ __forceinline__ float bf2f(__hip_bfloat16 v) { return __bfloat162float(v); }

// load 8 consecutive f32, round to bf16x8
static __device__ __forceinline__ bf16x8 ld8f_bf16(const float* __restrict__ p) {
    const float4 a = *(const float4*)p;
    const float4 b = *(const float4*)(p + 4);
    bf16x8 r;
    __hip_bfloat16* h = (__hip_bfloat16*)&r;
    h[0] = __float2bfloat16(a.x); h[1] = __float2bfloat16(a.y);
    h[2] = __float2bfloat16(a.z); h[3] = __float2bfloat16(a.w);
    h[4] = __float2bfloat16(b.x); h[5] = __float2bfloat16(b.y);
    h[6] = __float2bfloat16(b.z); h[7] = __float2bfloat16(b.w);
    return r;
}

// async global->LDS, 16B per lane; lds base must be wave-uniform
static __device__ __forceinline__ void gload_lds16(const __hip_bfloat16* g, __hip_bfloat16* l) {
    __builtin_amdgcn_global_load_lds(
        (const __attribute__((address_space(1))) void*)g,
        (__attribute__((address_space(3))) void*)l, 16, 0, 0);
}

// ---------------------------------------------------------------------------
// Kernel 0a/0b: f32 -> bf16 conversion (x, and the 4 weight matrices).
// ---------------------------------------------------------------------------
__global__ __launch_bounds__(256) void cvt_x(const float* __restrict__ src,
                                             __hip_bfloat16* __restrict__ dst) {
    const int i = (blockIdx.x * 256 + threadIdx.x) * 8;
    *(bf16x8*)(dst + i) = ld8f_bf16(src + i);
}

__global__ __launch_bounds__(256) void cvt_w(const float* __restrict__ w0,
                                             const float* __restrict__ w1,
                                             const float* __restrict__ w2,
                                             const float* __restrict__ w3,
                                             __hip_bfloat16* __restrict__ dst) {
    const float* srcs[4] = {w0, w1, w2, w3};
    const int b = blockIdx.y;
    const int i = (blockIdx.x * 256 + threadIdx.x) * 8;
    *(bf16x8*)(dst + (size_t)b * 589824 + i) = ld8f_bf16(srcs[b] + i);
}

// ---------------------------------------------------------------------------
// Kernel 1: fused QKV projection, 512 threads / 8 waves (wave tile 32x64).
// gload_lds staging from pre-converted bf16 (the proven-best structure).
// q pre-scaled by log2(e) for exp2 softmax.
// Outputs:
//   qr, kr : [((b*12+nh)*1024 + l)*64 + d]
//   v_t    : [((b*12+nh)*64 + d)*1024 + l]
// ---------------------------------------------------------------------------
__global__ __launch_bounds__(512) void qkv_gemm(
    const __hip_bfloat16* __restrict__ xb,
    const __hip_bfloat16* __restrict__ wb,
    const float* __restrict__ bq, const float* __restrict__ bk,
    const float* __restrict__ bv,
    const float* __restrict__ sinp, const float* __restrict__ cosp,
    __hip_bfloat16* __restrict__ qr, __hip_bfloat16* __restrict__ kr,
    __hip_bfloat16* __restrict__ v_t)
{
    __shared__ __align__(16) __hip_bfloat16 Alds[128 * 64];
    __shared__ __align__(16) __hip_bfloat16 Blds[128 * 64];

    const int t    = threadIdx.x;
    const int lane = t & 63;
    const int w    = t >> 6;           // 0..7
    const int wm   = w >> 1, wn = w & 1;
    const int l15  = lane & 15, lhi = lane >> 4;

    const int rm   = blockIdx.x;       // row tile 0..63
    const int cy   = blockIdx.y;       // 0..17
    const int wsel = cy / 6;           // 0=q,1=k,2=v
    const int cn   = cy % 6;

    const __hip_bfloat16* wgt = wb + (size_t)wsel * 589824;
    const float* bias = (wsel == 0) ? bq : (wsel == 1) ? bk : bv;

    const int srow = w * 16 + (lane >> 3);
    const int scol = (lane & 7) * 8;
    const __hip_bfloat16* asrc = xb  + (size_t)(rm * 128 + srow) * 768 + scol;
    const __hip_bfloat16* bsrc = wgt + (size_t)(cn * 128 + srow) * 768 + scol;

    f32x4 acc[2][4] = {};

    for (int k0 = 0; k0 < 768; k0 += 64) {
        __syncthreads();
        #pragma unroll
        for (int j = 0; j < 2; ++j) {
            gload_lds16(asrc + (size_t)j * 8 * 768 + k0, Alds + (w * 2 + j) * 512);
            gload_lds16(bsrc + (size_t)j * 8 * 768 + k0, Blds + (w * 2 + j) * 512);
        }
        __syncthreads();
        #pragma unroll
        for (int kk = 0; kk < 2; ++kk) {
            bf16x8 af[2], bfr[4];
            #pragma unroll
            for (int m = 0; m < 2; ++m)
                af[m] = *(const bf16x8*)&Alds[(wm * 32 + m * 16 + l15) * 64 + kk * 32 + lhi * 8];
            #pragma unroll
            for (int n = 0; n < 4; ++n)
                bfr[n] = *(const bf16x8*)&Blds[(wn * 64 + n * 16 + l15) * 64 + kk * 32 + lhi * 8];
            #pragma unroll
            for (int m = 0; m < 2; ++m)
                #pragma unroll
                for (int n = 0; n < 4; ++n)
                    acc[m][n] = __builtin_amdgcn_mfma_f32_16x16x32_bf16(af[m], bfr[n], acc[m][n], 0, 0, 0);
        }
    }

    // Epilogue: bias, RoPE (q,k), scaling (k: 0.125, q: log2e), scatter.
    #pragma unroll
    for (int m = 0; m < 2; ++m) {
        #pragma unroll
        for (int n = 0; n < 4; ++n) {
            const int gcol = cn * 128 + wn * 64 + n * 16 + l15;   // 0..767
            const float bcol = bias[gcol];
            const int nh = gcol >> 6, d = gcol & 63;
            const int grow0 = rm * 128 + wm * 32 + m * 16 + lhi * 4;
            const int bb = grow0 >> 10, ll0 = grow0 & 1023;
            if (wsel == 2) {
                bf16x4 pk;
                #pragma unroll
                for (int r = 0; r < 4; ++r)
                    ((__hip_bfloat16*)&pk)[r] = __float2bfloat16(acc[m][n][r] + bcol);
                *(bf16x4*)&v_t[(size_t)((bb * 12 + nh) * 64 + d) * 1024 + ll0] = pk;
            } else {
                #pragma unroll
                for (int r = 0; r < 4; ++r) {
                    const int ll = ll0 + r;
                    const float val = acc[m][n][r] + bcol;
                    const float other = __shfl_xor(val, 1);
                    const float cs = cosp[ll * 64 + d];
                    const float sn = sinp[ll * 64 + d];
                    float res = val * cs + ((d & 1) ? other : -other) * sn;
                    res *= (wsel == 1) ? 0.125f : LOG2E;
                    __hip_bfloat16* dst = (wsel == 1) ? kr : qr;
                    dst[(size_t)((bb * 12 + nh) * 1024 + ll) * 64 + d] = __float2bfloat16(res);
                }
            }
        }
    }
}

// ---------------------------------------------------------------------------
// Kernel 2: flash-style attention, swapped-operand, LDS-staged K/V with
// register prefetch; static exp2 softmax; mask register-prefetched one kt
// ahead (r13 version, kept to isolate its effect this round).
// ---------------------------------------------------------------------------
__global__ __launch_bounds__(256) void attn_kernel(
    const __hip_bfloat16* __restrict__ qr,
    const __hip_bfloat16* __restrict__ kr,
    const __hip_bfloat16* __restrict__ v_t,
    const float* __restrict__ mask,
    __hip_bfloat16* __restrict__ attn_out)
{
    __shared__ __align__(16) __hip_bfloat16 Klds[64][LDS_PAD];
    __shared__ __align__(16) __hip_bfloat16 Vtlds[64][LDS_PAD];
    __shared__ __align__(16) __hip_bfloat16 Pq[4][16][LDS_PAD];

    const int qt = blockIdx.x;      // 0..15
    const int bh = blockIdx.y;      // 0..95
    const int b = bh / 12, nh = bh % 12;

    const int t = threadIdx.x, lane = t & 63, w = t >> 6;
    const int l15 = lane & 15, lhi = lane >> 4;
    const int qg = qt * 64 + w * 16 + l15;

    bf16x8 qf[2];   // q pre-scaled by log2(e)
    qf[0] = *(const bf16x8*)&qr[((size_t)bh * 1024 + qg) * 64 + lhi * 8];
    qf[1] = *(const bf16x8*)&qr[((size_t)bh * 1024 + qg) * 64 + 32 + lhi * 8];

    f32x4 o[4] = {};
    float l_run = 0.f;

    const int srow = t >> 3;
    const int scol = (t & 7) * 8;

    const float* mbase = mask + ((size_t)nh << 20) + (size_t)qg * 1024;

    // prologue: prefetch kt=0 K/V tiles and mask
    bf16x8 kb0, kb1, vb0, vb1;
    float4 mv[4];
    {
        const size_t kbase = ((size_t)bh * 1024) * 64;
        kb0 = *(const bf16x8*)&kr[kbase + (size_t)srow * 64 + scol];
        kb1 = *(const bf16x8*)&kr[kbase + (size_t)(srow + 32) * 64 + scol];
        const size_t vbase = (size_t)bh * 64 * 1024;
        vb0 = *(const bf16x8*)&v_t[vbase + (size_t)srow * 1024 + scol];
        vb1 = *(const bf16x8*)&v_t[vbase + (size_t)(srow + 32) * 1024 + scol];
        #pragma unroll
        for (int n = 0; n < 4; ++n)
            mv[n] = *(const float4*)&mbase[n * 16 + lhi * 4];
    }

    for (int kt = 0; kt < 16; ++kt) {
        *(bf16x8*)&Klds[srow][scol]       = kb0;
        *(bf16x8*)&Klds[srow + 32][scol]  = kb1;
        *(bf16x8*)&Vtlds[srow][scol]      = vb0;
        *(bf16x8*)&Vtlds[srow + 32][scol] = vb1;
        __syncthreads();

        float4 mvn[4];
        if (kt < 15) {   // prefetch next tile's K/V AND mask
            const size_t kbase = ((size_t)bh * 1024 + (kt + 1) * 64) * 64;
            kb0 = *(const bf16x8*)&kr[kbase + (size_t)srow * 64 + scol];
            kb1 = *(const bf16x8*)&kr[kbase + (size_t)(srow + 32) * 64 + scol];
            const size_t vbase = (size_t)bh * 64 * 1024 + (kt + 1) * 64;
            vb0 = *(const bf16x8*)&v_t[vbase + (size_t)srow * 1024 + scol];
            vb1 = *(const bf16x8*)&v_t[vbase + (size_t)(srow + 32) * 1024 + scol];
            #pragma unroll
            for (int n = 0; n < 4; ++n)
                mvn[n] = *(const float4*)&mbase[(kt + 1) * 64 + n * 16 + lhi * 4];
        }

        f32x4 s[4] = {};
        __builtin_amdgcn_s_setprio(1);
        #pragma unroll
        for (int n = 0; n < 4; ++n) {
            const bf16x8 kf0 = *(const bf16x8*)&Klds[n * 16 + l15][lhi * 8];
            const bf16x8 kf1 = *(const bf16x8*)&Klds[n * 16 + l15][32 + lhi * 8];
            s[n] = __builtin_amdgcn_mfma_f32_16x16x32_bf16(kf0, qf[0], s[n], 0, 0, 0);
            s[n] = __builtin_amdgcn_mfma_f32_16x16x32_bf16(kf1, qf[1], s[n], 0, 0, 0);
        }
        __builtin_amdgcn_s_setprio(0);

        // static softmax: P = exp2(s + mask*log2e); pure-sum l accumulation
        #pragma unroll
        for (int n = 0; n < 4; ++n) {
            bf16x4 pk;
            #pragma unroll
            for (int r = 0; r < 4; ++r) {
                const float p = exp2f(fmaf(((const float*)&mv[n])[r], LOG2E, s[n][r]));
                l_run += p;
                ((__hip_bfloat16*)&pk)[r] = __float2bfloat16(p);
            }
            *(bf16x4*)&Pq[w][l15][n * 16 + lhi * 4] = pk;
        }
        asm volatile("s_waitcnt lgkmcnt(0)" ::: "memory");
        __builtin_amdgcn_sched_barrier(0);

        __builtin_amdgcn_s_setprio(1);
        #pragma unroll
        for (int ks = 0; ks < 2; ++ks) {
            const bf16x8 pf = *(const bf16x8*)&Pq[w][l15][ks * 32 + lhi * 8];
            #pragma unroll
            for (int m = 0; m < 4; ++m) {
                const bf16x8 vf = *(const bf16x8*)&Vtlds[m * 16 + l15][ks * 32 + lhi * 8];
                o[m] = __builtin_amdgcn_mfma_f32_16x16x32_bf16(vf, pf, o[m], 0, 0, 0);
            }
        }
        __builtin_amdgcn_s_setprio(0);
        __syncthreads();

        #pragma unroll
        for (int n = 0; n < 4; ++n) mv[n] = mvn[n];
    }

    // one final cross-lane l reduce (q row spans lhi = 0..3)
    l_run += __shfl_xor(l_run, 16);
    l_run += __shfl_xor(l_run, 32);

    const float rl = 1.f / l_run;
    #pragma unroll
    for (int m = 0; m < 4; ++m) {
        bf16x4 pk;
        #pragma unroll
        for (int r = 0; r < 4; ++r)
            ((__hip_bfloat16*)&pk)[r] = __float2bfloat16(o[m][r] * rl);
        *(bf16x4*)&attn_out[((size_t)b * 1024 + qg) * 768 + nh * 64 + m * 16 + lhi * 4] = pk;
    }
}

// ---------------------------------------------------------------------------
// Kernel 3: depthwise 5x5 conv (LEPE), fused add into aout (in-place).
// ---------------------------------------------------------------------------
__global__ __launch_bounds__(256) void lepe_conv(
    const __hip_bfloat16* __restrict__ v_t,
    const float* __restrict__ lw,
    const float* __restrict__ lb,
    __hip_bfloat16* __restrict__ aout)
{
    __shared__ __hip_bfloat16 img[8][1024];

    const int b  = blockIdx.x / 96;
    const int cg = blockIdx.x % 96;
    const int c0 = cg * 8;
    const int t  = threadIdx.x;

    for (int i = t; i < 2048; i += 256) {
        const int ci = i >> 8, l4 = (i & 255) << 2;
        const int c = c0 + ci, nh = c >> 6, d = c & 63;
        *(bf16x4*)&img[ci][l4] =
            *(const bf16x4*)&v_t[(size_t)((b * 12 + nh) * 64 + d) * 1024 + l4];
    }
    __syncthreads();

    const int ci = t & 7, c = c0 + ci;
    float wt[25];
    #pragma unroll
    for (int k = 0; k < 25; ++k) wt[k] = lw[k * 768 + c];
    const float bias = lb[c];

    for (int l0 = t >> 3; l0 < 1024; l0 += 32) {
        const int h = l0 >> 5, w = l0 & 31;
        float s = bias;
        #pragma unroll
        for (int dy = 0; dy < 5; ++dy) {
            const int hy = h + dy - 2;
            if (hy < 0 || hy > 31) continue;
            #pragma unroll
            for (int dx = 0; dx < 5; ++dx) {
                const int wx = w + dx - 2;
                if (wx < 0 || wx > 31) continue;
                s += bf2f(img[ci][hy * 32 + wx]) * wt[dy * 5 + dx];
            }
        }
        const size_t idx = (size_t)(b * 1024 + l0) * 768 + c;
        aout[idx] = __float2bfloat16(s + bf2f(aout[idx]));
    }
}

// ---------------------------------------------------------------------------
// Kernel 4: output projection (512 threads / 8 waves, wave tile 32x64,
// gload_lds staging). out = aout @ wo^T + bo  (bf16 in, f32 out)
// ---------------------------------------------------------------------------
__global__ __launch_bounds__(512) void proj_gemm(
    const __hip_bfloat16* __restrict__ aout,
    const __hip_bfloat16* __restrict__ wb,
    const float* __restrict__ bo,
    float* __restrict__ out)
{
    __shared__ __align__(16) __hip_bfloat16 Alds[128 * 64];
    __shared__ __align__(16) __hip_bfloat16 Blds[128 * 64];

    const int t    = threadIdx.x;
    const int lane = t & 63;
    const int w    = t >> 6;
    const int wm   = w >> 1, wn = w & 1;
    const int l15  = lane & 15, lhi = lane >> 4;

    const int rm = blockIdx.x, cn = blockIdx.y;
    const __hip_bfloat16* wgt = wb + (size_t)3 * 589824;

    const int srow = w * 16 + (lane >> 3);
    const int scol = (lane & 7) * 8;
    const __hip_bfloat16* asrc = aout + (size_t)(rm * 128 + srow) * 768 + scol;
    const __hip_bfloat16* bsrc = wgt  + (size_t)(cn * 128 + srow) * 768 + scol;

    f32x4 acc[2][4] = {};

    for (int k0 = 0; k0 < 768; k0 += 64) {
        __syncthreads();
        #pragma unroll
        for (int j = 0; j < 2; ++j) {
            gload_lds16(asrc + (size_t)j * 8 * 768 + k0, Alds + (w * 2 + j) * 512);
            gload_lds16(bsrc + (size_t)j * 8 * 768 + k0, Blds + (w * 2 + j) * 512);
        }
        __syncthreads();
        #pragma unroll
        for (int kk = 0; kk < 2; ++kk) {
            bf16x8 af[2], bfr[4];
            #pragma unroll
            for (int m = 0; m < 2; ++m)
                af[m] = *(const bf16x8*)&Alds[(wm * 32 + m * 16 + l15) * 64 + kk * 32 + lhi * 8];
            #pragma unroll
            for (int n = 0; n < 4; ++n)
                bfr[n] = *(const bf16x8*)&Blds[(wn * 64 + n * 16 + l15) * 64 + kk * 32 + lhi * 8];
            #pragma unroll
            for (int m = 0; m < 2; ++m)
                #pragma unroll
                for (int n = 0; n < 4; ++n)
                    acc[m][n] = __builtin_amdgcn_mfma_f32_16x16x32_bf16(af[m], bfr[n], acc[m][n], 0, 0, 0);
        }
    }

    #pragma unroll
    for (int m = 0; m < 2; ++m)
        #pragma unroll
        for (int n = 0; n < 4; ++n) {
            const int gcol = cn * 128 + wn * 64 + n * 16 + l15;
            const float bcol = bo[gcol];
            #pragma unroll
            for (int r = 0; r < 4; ++r) {
                const int grow = rm * 128 + wm * 32 + m * 16 + lhi * 4 + r;
                out[(size_t)grow * 768 + gcol] = acc[m][n][r] + bcol;
            }
        }
}

// ---------------------------------------------------------------------------
extern "C" void kernel_launch(void* const* d_in, const int* in_sizes, int n_in,
                              void* d_out, int out_size, void* d_ws, size_t ws_size,
                              hipStream_t stream) {
    const float* x    = (const float*)d_in[0];
    const float* sinp = (const float*)d_in[1];
    const float* cosp = (const float*)d_in[2];
    const float* mask = (const float*)d_in[3];
    const float* wq   = (const float*)d_in[4];
    const float* bq   = (const float*)d_in[5];
    const float* wk   = (const float*)d_in[6];
    const float* bk   = (const float*)d_in[7];
    const float* wvw  = (const float*)d_in[8];
    const float* bv   = (const float*)d_in[9];
    const float* lw   = (const float*)d_in[10];
    const float* lb   = (const float*)d_in[11];
    const float* wo   = (const float*)d_in[12];
    const float* bo   = (const float*)d_in[13];
    float* out = (float*)d_out;

    char* ws = (char*)d_ws;
    const size_t SZ = (size_t)8192 * 768 * 2;    // 12.58 MB per bf16 buffer
    __hip_bfloat16* qr   = (__hip_bfloat16*)(ws);
    __hip_bfloat16* kr   = (__hip_bfloat16*)(ws + SZ);
    __hip_bfloat16* v_t  = (__hip_bfloat16*)(ws + 2 * SZ);
    __hip_bfloat16* xb   = (__hip_bfloat16*)(ws + 3 * SZ);
    __hip_bfloat16* wb   = (__hip_bfloat16*)(ws + 4 * SZ);   // 4x768x768 bf16
    __hip_bfloat16* aout = xb;   // xb dead after qkv_gemm

    cvt_x<<<dim3(3072), 256, 0, stream>>>(x, xb);
    cvt_w<<<dim3(288, 4), 256, 0, stream>>>(wq, wk, wvw, wo, wb);
    qkv_gemm<<<dim3(64, 18), 512, 0, stream>>>(xb, wb, bq, bk, bv,
                                               sinp, cosp, qr, kr, v_t);
    attn_kernel<<<dim3(16, 96), 256, 0, stream>>>(qr, kr, v_t, mask, aout);
    lepe_conv<<<dim3(768), 256, 0, stream>>>(v_t, lw, lb, aout);
    proj_gemm<<<dim3(64, 6), 512, 0, stream>>>(aout, wb, bo, out);
}